// Round 2
// baseline (1069.520 us; speedup 1.0000x reference)
//
#include <hip/hip_runtime.h>
#include <hip/hip_bf16.h>
#include <math.h>

// Problem constants: B=4, L=S=2048, H=8, E=64, T=1.0
// I/O dtype: float32 (per reference; round-1 NaN proved buffers are fp32,
// bf16 reinterpretation injected NaNs via garbage mantissa halves).
#define LOGN 11
#define NN   2048
#define NF   1025          // NN/2 + 1 frequency bins
#define TWO_PI 6.283185307179586f
#define INV_SQRT_N 0.022097086912079608f   // 1/sqrt(2048)

// ---------------------------------------------------------------------------
// Shared radix-2 DIT butterfly stages (input pre-bit-reversed in buf).
// tw[k] = e^{sign*2*pi*i*k/N} for k=0..N/2-1.
// ---------------------------------------------------------------------------
__device__ __forceinline__ void fft_stages(float2* buf, const float2* tw, int tid)
{
    for (int st = 1; st <= LOGN; st++) {
        int half = 1 << (st - 1);
        #pragma unroll
        for (int it = 0; it < 4; it++) {
            int j   = tid + 256 * it;          // butterfly index 0..1023
            int pos = j & (half - 1);
            int grp = j >> (st - 1);
            int i0  = (grp << st) + pos;
            int i1  = i0 + half;
            float2 w = tw[pos << (LOGN - st)];
            float2 a = buf[i0];
            float2 b = buf[i1];
            float2 bw = make_float2(b.x * w.x - b.y * w.y,
                                    b.x * w.y + b.y * w.x);
            buf[i0] = make_float2(a.x + bw.x, a.y + bw.y);
            buf[i1] = make_float2(a.x - bw.x, a.y - bw.y);
        }
        __syncthreads();
    }
}

// ---------------------------------------------------------------------------
// Forward rFFT (ortho) for q,k,v.  One block per (tensor, b, h, e) series.
// Input  layout: [B, T=2048, H, E] fp32 (stride 512 elems along time).
// Output layout: [bh*64+e][x] float2, x = 0..1024.
// ---------------------------------------------------------------------------
__global__ __launch_bounds__(256) void fft_fwd(const float* __restrict__ q,
                                               const float* __restrict__ k,
                                               const float* __restrict__ v,
                                               float2* __restrict__ qft,
                                               float2* __restrict__ kft,
                                               float2* __restrict__ vft)
{
    __shared__ float2 buf[NN];
    __shared__ float2 tw[NN / 2];

    int bid    = blockIdx.x;
    int tensor = bid >> 11;          // 0:q 1:k 2:v
    int s      = bid & 2047;         // b*512 + h*64 + e
    int tid    = threadIdx.x;

    const float* in = (tensor == 0) ? q : (tensor == 1) ? k : v;
    float2* outp    = (tensor == 0) ? qft : (tensor == 1) ? kft : vft;

    for (int i = tid; i < NN / 2; i += 256) {
        float ang = -TWO_PI * (float)i / (float)NN;   // forward: e^{-i...}
        float sv, cv;
        sincosf(ang, &sv, &cv);
        tw[i] = make_float2(cv, sv);
    }

    int e = s & 63;
    const float* src =
        in + ((size_t)(s >> 9)) * (2048 * 512) + (((s >> 6) & 7) * 64) + e;
    for (int i = 0; i < 8; i++) {
        int t = tid + 256 * i;
        float xv = src[(size_t)t * 512];
        buf[__brev((unsigned)t) >> (32 - LOGN)] = make_float2(xv, 0.f);
    }
    __syncthreads();

    fft_stages(buf, tw, tid);

    float2* dst = outp + (size_t)s * NF;
    for (int x = tid; x < NF; x += 256) {
        float2 vv = buf[x];
        dst[x] = make_float2(vv.x * INV_SQRT_N, vv.y * INV_SQRT_N);
    }
}

// ---------------------------------------------------------------------------
// Flash attention over frequency bins, fp32.
// One block per (bh, 32-row x-block). 256 threads.
// QK mapping:  ty=tid/16 -> rows 2ty,2ty+1 ; tx=tid%16 -> cols 2tx,2tx+1
// PV mapping:  same rows ; ee = 8*tx .. 8*tx+7  (128 = re[0..63], im[0..63])
// ---------------------------------------------------------------------------
#define BR 32
#define BC 32

struct __align__(16) FlashLds {
    float Qs[BR][132];   // [row][kk] kk<64: re(e), kk>=64: im(e-64); pad->132
    float Ks[BC][132];
    float Vs[BC][132];   // [y][ee]  ee<64: vr, >=64: vi
    float Ps[BR][33];
    float Ml[BR];
    float Ll[BR];
    float Al[BR];
};

#define CDOT(qr, qi, kr, ki, re, im)                                          \
    re += qr.x * kr.x + qi.x * ki.x;  im += qi.x * kr.x - qr.x * ki.x;        \
    re += qr.y * kr.y + qi.y * ki.y;  im += qi.y * kr.y - qr.y * ki.y;        \
    re += qr.z * kr.z + qi.z * ki.z;  im += qi.z * kr.z - qr.z * ki.z;        \
    re += qr.w * kr.w + qi.w * ki.w;  im += qi.w * kr.w - qr.w * ki.w;

__global__ __launch_bounds__(256) void flash_attn(const float2* __restrict__ qft,
                                                  const float2* __restrict__ kft,
                                                  const float2* __restrict__ vft,
                                                  float* __restrict__ oft)
{
    __shared__ FlashLds L;
    int bid = blockIdx.x;
    int bh  = bid / 33;
    int x0  = (bid % 33) * BR;
    int tid = threadIdx.x;
    int ty  = tid >> 4;
    int tx  = tid & 15;
    int r0  = ty * 2;
    int c0  = tx * 2;
    int ee  = tx * 8;

    const float2* qbase = qft + (size_t)bh * 64 * NF;
    const float2* kbase = kft + (size_t)bh * 64 * NF;
    const float2* vbase = vft + (size_t)bh * 64 * NF;

    // Stage Q block (32 rows x 64 complex) into LDS.
    for (int jj = 0; jj < 8; jj++) {
        int flat = tid + 256 * jj;
        int r = flat & 31;
        int e = flat >> 5;
        int x = x0 + r;
        float2 val = (x < NF) ? qbase[(size_t)e * NF + x] : make_float2(0.f, 0.f);
        L.Qs[r][e]      = val.x;
        L.Qs[r][64 + e] = val.y;
    }
    if (tid < BR) { L.Ml[tid] = -1e30f; L.Ll[tid] = 0.f; }

    float acc0[8], acc1[8];
    #pragma unroll
    for (int j = 0; j < 8; j++) { acc0[j] = 0.f; acc1[j] = 0.f; }
    __syncthreads();

    for (int y0 = 0; y0 < NF; y0 += BC) {
        // Stage K/V tile.
        for (int jj = 0; jj < 8; jj++) {
            int flat = tid + 256 * jj;
            int i = flat & 31;
            int e = flat >> 5;
            int y = y0 + i;
            float2 kv = (y < NF) ? kbase[(size_t)e * NF + y] : make_float2(0.f, 0.f);
            float2 vv = (y < NF) ? vbase[(size_t)e * NF + y] : make_float2(0.f, 0.f);
            L.Ks[i][e]      = kv.x;  L.Ks[i][64 + e] = kv.y;
            L.Vs[i][e]      = vv.x;  L.Vs[i][64 + e] = vv.y;
        }
        __syncthreads();

        // ----- QK: 2x2 complex scores per thread -----
        float re00 = 0, re01 = 0, re10 = 0, re11 = 0;
        float im00 = 0, im01 = 0, im10 = 0, im11 = 0;
        #pragma unroll 4
        for (int e4 = 0; e4 < 64; e4 += 4) {
            float4 qr0 = *(const float4*)&L.Qs[r0][e4];
            float4 qi0 = *(const float4*)&L.Qs[r0][64 + e4];
            float4 qr1 = *(const float4*)&L.Qs[r0 + 1][e4];
            float4 qi1 = *(const float4*)&L.Qs[r0 + 1][64 + e4];
            float4 kr0 = *(const float4*)&L.Ks[c0][e4];
            float4 ki0 = *(const float4*)&L.Ks[c0][64 + e4];
            float4 kr1 = *(const float4*)&L.Ks[c0 + 1][e4];
            float4 ki1 = *(const float4*)&L.Ks[c0 + 1][64 + e4];
            CDOT(qr0, qi0, kr0, ki0, re00, im00)
            CDOT(qr0, qi0, kr1, ki1, re01, im01)
            CDOT(qr1, qi1, kr0, ki0, re10, im10)
            CDOT(qr1, qi1, kr1, ki1, re11, im11)
        }

        bool vc0 = (y0 + c0) < NF, vc1 = (y0 + c0 + 1) < NF;
        // |scores|/sqrt(E): scale 1/8 (T = 1)
        float sa00 = vc0 ? 0.125f * sqrtf(re00 * re00 + im00 * im00) : -1e30f;
        float sa01 = vc1 ? 0.125f * sqrtf(re01 * re01 + im01 * im01) : -1e30f;
        float sa10 = vc0 ? 0.125f * sqrtf(re10 * re10 + im10 * im10) : -1e30f;
        float sa11 = vc1 ? 0.125f * sqrtf(re11 * re11 + im11 * im11) : -1e30f;

        // Row max across the 16 tx lanes (same wave).
        float tm0 = fmaxf(sa00, sa01), tm1 = fmaxf(sa10, sa11);
        #pragma unroll
        for (int d = 1; d < 16; d <<= 1) {
            tm0 = fmaxf(tm0, __shfl_xor(tm0, d, 64));
            tm1 = fmaxf(tm1, __shfl_xor(tm1, d, 64));
        }
        float mold0 = L.Ml[r0], mold1 = L.Ml[r0 + 1];
        float mnew0 = fmaxf(mold0, tm0), mnew1 = fmaxf(mold1, tm1);

        float p00 = vc0 ? __expf(sa00 - mnew0) : 0.f;
        float p01 = vc1 ? __expf(sa01 - mnew0) : 0.f;
        float p10 = vc0 ? __expf(sa10 - mnew1) : 0.f;
        float p11 = vc1 ? __expf(sa11 - mnew1) : 0.f;
        float ps0 = p00 + p01, ps1 = p10 + p11;
        #pragma unroll
        for (int d = 1; d < 16; d <<= 1) {
            ps0 += __shfl_xor(ps0, d, 64);
            ps1 += __shfl_xor(ps1, d, 64);
        }
        if (tx == 0) {
            float al0 = (mold0 <= -1e29f) ? 0.f : __expf(mold0 - mnew0);
            float al1 = (mold1 <= -1e29f) ? 0.f : __expf(mold1 - mnew1);
            L.Al[r0] = al0;       L.Al[r0 + 1] = al1;
            L.Ll[r0] = L.Ll[r0] * al0 + ps0;
            L.Ll[r0 + 1] = L.Ll[r0 + 1] * al1 + ps1;
            L.Ml[r0] = mnew0;     L.Ml[r0 + 1] = mnew1;
        }
        L.Ps[r0][c0] = p00;      L.Ps[r0][c0 + 1] = p01;
        L.Ps[r0 + 1][c0] = p10;  L.Ps[r0 + 1][c0 + 1] = p11;
        __syncthreads();

        // ----- PV: rescale + accumulate -----
        float al0 = L.Al[r0], al1 = L.Al[r0 + 1];
        #pragma unroll
        for (int j = 0; j < 8; j++) { acc0[j] *= al0; acc1[j] *= al1; }
        #pragma unroll 4
        for (int i = 0; i < BC; i++) {
            float p0 = L.Ps[r0][i], p1 = L.Ps[r0 + 1][i];
            float4 va = *(const float4*)&L.Vs[i][ee];
            float4 vb = *(const float4*)&L.Vs[i][ee + 4];
            acc0[0] = fmaf(p0, va.x, acc0[0]);
            acc0[1] = fmaf(p0, va.y, acc0[1]);
            acc0[2] = fmaf(p0, va.z, acc0[2]);
            acc0[3] = fmaf(p0, va.w, acc0[3]);
            acc0[4] = fmaf(p0, vb.x, acc0[4]);
            acc0[5] = fmaf(p0, vb.y, acc0[5]);
            acc0[6] = fmaf(p0, vb.z, acc0[6]);
            acc0[7] = fmaf(p0, vb.w, acc0[7]);
            acc1[0] = fmaf(p1, va.x, acc1[0]);
            acc1[1] = fmaf(p1, va.y, acc1[1]);
            acc1[2] = fmaf(p1, va.z, acc1[2]);
            acc1[3] = fmaf(p1, va.w, acc1[3]);
            acc1[4] = fmaf(p1, vb.x, acc1[4]);
            acc1[5] = fmaf(p1, vb.y, acc1[5]);
            acc1[6] = fmaf(p1, vb.z, acc1[6]);
            acc1[7] = fmaf(p1, vb.w, acc1[7]);
        }
        __syncthreads();
    }

    // Epilogue: normalize and store to [bh][x][128] (coalesced over ee).
    float l0 = L.Ll[r0], l1 = L.Ll[r0 + 1];
    float inv0 = (l0 > 0.f) ? 1.f / l0 : 0.f;
    float inv1 = (l1 > 0.f) ? 1.f / l1 : 0.f;
    int xr0 = x0 + r0, xr1 = x0 + r0 + 1;
    if (xr0 < NF) {
        float* d0 = oft + ((size_t)bh * NF + xr0) * 128 + ee;
        #pragma unroll
        for (int j = 0; j < 8; j++) d0[j] = acc0[j] * inv0;
    }
    if (xr1 < NF) {
        float* d1 = oft + ((size_t)bh * NF + xr1) * 128 + ee;
        #pragma unroll
        for (int j = 0; j < 8; j++) d1[j] = acc1[j] * inv1;
    }
}

// ---------------------------------------------------------------------------
// Inverse rFFT (ortho): Hermitian-extend 1025 bins -> 2048, iFFT, real part.
// One block per (b,h,e). Output [B, T, H, E] fp32.
// ---------------------------------------------------------------------------
__global__ __launch_bounds__(256) void fft_inv(const float* __restrict__ oft,
                                               float* __restrict__ out)
{
    __shared__ float2 buf[NN];
    __shared__ float2 tw[NN / 2];

    int s   = blockIdx.x;         // b*512 + h*64 + e
    int tid = threadIdx.x;

    for (int i = tid; i < NN / 2; i += 256) {
        float ang = TWO_PI * (float)i / (float)NN;    // inverse: e^{+i...}
        float sv, cv;
        sincosf(ang, &sv, &cv);
        tw[i] = make_float2(cv, sv);
    }

    int e  = s & 63;
    int bh = s >> 6;
    const float* src = oft + (size_t)bh * NF * 128;
    for (int i = 0; i < 8; i++) {
        int t  = tid + 256 * i;
        int xs = (t <= 1024) ? t : (NN - t);
        float re = src[(size_t)xs * 128 + e];
        float im = src[(size_t)xs * 128 + 64 + e];
        if (t > 1024) im = -im;                        // conj for mirror bins
        buf[__brev((unsigned)t) >> (32 - LOGN)] = make_float2(re, im);
    }
    __syncthreads();

    fft_stages(buf, tw, tid);

    float* dst =
        out + ((size_t)(s >> 9)) * (2048 * 512) + (((s >> 6) & 7) * 64) + e;
    for (int i = 0; i < 8; i++) {
        int t = tid + 256 * i;
        dst[(size_t)t * 512] = buf[t].x * INV_SQRT_N;
    }
}

// ---------------------------------------------------------------------------
extern "C" void kernel_launch(void* const* d_in, const int* in_sizes, int n_in,
                              void* d_out, int out_size, void* d_ws, size_t ws_size,
                              hipStream_t stream)
{
    const float* q = (const float*)d_in[0];
    const float* k = (const float*)d_in[1];
    const float* v = (const float*)d_in[2];
    // d_in[3] (mask) is unused by the reference module.
    float* out = (float*)d_out;

    char* ws = (char*)d_ws;
    const size_t ftsz = (size_t)32 * 64 * NF * sizeof(float2);  // 16.8 MB each
    float2* qft = (float2*)(ws);
    float2* kft = (float2*)(ws + ftsz);
    float2* vft = (float2*)(ws + 2 * ftsz);
    float*  oft = (float*)(ws + 3 * ftsz);                      // [32][1025][128]

    hipLaunchKernelGGL(fft_fwd, dim3(3 * 2048), dim3(256), 0, stream,
                       q, k, v, qft, kft, vft);
    hipLaunchKernelGGL(flash_attn, dim3(32 * 33), dim3(256), 0, stream,
                       qft, kft, vft, oft);
    hipLaunchKernelGGL(fft_inv, dim3(2048), dim3(256), 0, stream, oft, out);
}

// Round 3
// 370.210 us; speedup vs baseline: 2.8890x; 2.8890x over previous
//
#include <hip/hip_runtime.h>
#include <hip/hip_bf16.h>
#include <math.h>

// Problem constants: B=4, L=S=2048, H=8, E=64, T=1.0.  I/O fp32.
#define LOGN 11
#define NN   2048
#define NF   1025
#define NYP  1056          // NF padded to 33 tiles of 32 (pad rows zeroed)
#define TWO_PI 6.283185307179586f
#define INV_SQRT_N 0.022097086912079608f   // 1/sqrt(2048)

typedef __attribute__((ext_vector_type(8))) short bhalf8;   // 8 bf16 = 4 VGPRs
typedef __attribute__((ext_vector_type(4))) float f32x4;

#define MFMA16(a, b, c) __builtin_amdgcn_mfma_f32_16x16x32_bf16(a, b, c, 0, 0, 0)

__device__ __forceinline__ unsigned short f2bf(float f) {
    union { float f; unsigned u; } v; v.f = f;
    unsigned r = v.u + 0x7FFFu + ((v.u >> 16) & 1u);   // RNE
    return (unsigned short)(r >> 16);
}

// ---------------------------------------------------------------------------
// Radix-2 DIT butterfly stages (input pre-bit-reversed in buf).
// ---------------------------------------------------------------------------
__device__ __forceinline__ void fft_stages(float2* buf, const float2* tw, int tid)
{
    for (int st = 1; st <= LOGN; st++) {
        int half = 1 << (st - 1);
        #pragma unroll
        for (int it = 0; it < 4; it++) {
            int j   = tid + 256 * it;
            int pos = j & (half - 1);
            int grp = j >> (st - 1);
            int i0  = (grp << st) + pos;
            int i1  = i0 + half;
            float2 w = tw[pos << (LOGN - st)];
            float2 a = buf[i0];
            float2 b = buf[i1];
            float2 bw = make_float2(b.x * w.x - b.y * w.y,
                                    b.x * w.y + b.y * w.x);
            buf[i0] = make_float2(a.x + bw.x, a.y + bw.y);
            buf[i1] = make_float2(a.x - bw.x, a.y - bw.y);
        }
        __syncthreads();
    }
}

// ---------------------------------------------------------------------------
// Forward rFFT (ortho).  One block per (tensor, bh, e) series.
// q,k -> float2 [bh*64+e][1025]  (q needed fp32 for in-register A-frags;
//                                 k goes through kpack transpose)
// v   -> bf16 planes Vt[bh][kk=0..127][1056]  (kk<64: re(e), >=64: im(e))
// ---------------------------------------------------------------------------
__global__ __launch_bounds__(256) void fft_fwd(const float* __restrict__ q,
                                               const float* __restrict__ k,
                                               const float* __restrict__ v,
                                               float2* __restrict__ qft,
                                               float2* __restrict__ kft,
                                               unsigned short* __restrict__ Vt)
{
    __shared__ float2 buf[NN];
    __shared__ float2 tw[NN / 2];

    int bid    = blockIdx.x;
    int tensor = bid >> 11;          // 0:q 1:k 2:v
    int s      = bid & 2047;         // bh*64 + e
    int tid    = threadIdx.x;

    const float* in = (tensor == 0) ? q : (tensor == 1) ? k : v;

    for (int i = tid; i < NN / 2; i += 256) {
        float ang = -TWO_PI * (float)i / (float)NN;
        float sv, cv;
        __sincosf(ang, &sv, &cv);
        tw[i] = make_float2(cv, sv);
    }

    int e = s & 63;
    const float* src =
        in + ((size_t)(s >> 9)) * (2048 * 512) + (((s >> 6) & 7) * 64) + e;
    for (int i = 0; i < 8; i++) {
        int t = tid + 256 * i;
        float xv = src[(size_t)t * 512];
        buf[__brev((unsigned)t) >> (32 - LOGN)] = make_float2(xv, 0.f);
    }
    __syncthreads();

    fft_stages(buf, tw, tid);

    if (tensor == 2) {
        unsigned short* dre = Vt + ((size_t)(s >> 6) * 128 + e) * NYP;
        unsigned short* dim = dre + (size_t)64 * NYP;
        for (int y = tid; y < NYP; y += 256) {
            float2 vv = (y < NF) ? buf[y] : make_float2(0.f, 0.f);
            dre[y] = f2bf(vv.x * INV_SQRT_N);
            dim[y] = f2bf(vv.y * INV_SQRT_N);
        }
    } else {
        float2* dst = ((tensor == 0) ? qft : kft) + (size_t)s * NF;
        for (int x = tid; x < NF; x += 256) {
            float2 vv = buf[x];
            dst[x] = make_float2(vv.x * INV_SQRT_N, vv.y * INV_SQRT_N);
        }
    }
}

// ---------------------------------------------------------------------------
// Transpose K spectra: kft float2 [bh*64+e][1025] -> Kp bf16 [bh][1056][128]
// (row y: kk<64 = re(e=kk), kk>=64 = im; pad rows y>=1025 zeroed)
// ---------------------------------------------------------------------------
__global__ __launch_bounds__(256) void kpack(const float2* __restrict__ kft,
                                             unsigned short* __restrict__ Kp)
{
    __shared__ unsigned short Ts[32][136];   // 272 B rows: 16B-aligned b128
    int y0  = blockIdx.x * 32;
    int bh  = blockIdx.y;
    int tid = threadIdx.x;

    int e = tid >> 2, c = tid & 3;
    const float2* src = kft + ((size_t)bh * 64 + e) * NF;
    #pragma unroll
    for (int i = 0; i < 8; i++) {
        int y = y0 + c * 8 + i;
        float2 vv = (y < NF) ? src[y] : make_float2(0.f, 0.f);
        Ts[c * 8 + i][e]      = f2bf(vv.x);
        Ts[c * 8 + i][64 + e] = f2bf(vv.y);
    }
    __syncthreads();

    int yy = tid >> 3, cc = tid & 7;
    uint4 a = *(const uint4*)&Ts[yy][cc * 16];
    uint4 b = *(const uint4*)&Ts[yy][cc * 16 + 8];
    unsigned short* dst = Kp + ((size_t)bh * NYP + y0 + yy) * 128 + cc * 16;
    *(uint4*)dst       = a;
    *(uint4*)(dst + 8) = b;
}

// ---------------------------------------------------------------------------
// MFMA flash attention over frequency bins.
// Block: 4 waves x 16 rows = 64 x-bins; loop over 33 y-tiles of 32.
// QK: S_re = [Qr|Qi].[Kr|Ki]^T, S_im = [Qi|-Qr].[Kr|Ki]^T  (K=128, bf16 MFMA)
// softmax (fp32, online) in C-layout; P -> per-wave LDS -> A-frag for PV.
// ---------------------------------------------------------------------------
__global__ __launch_bounds__(256) void flash_mfma(
    const float2* __restrict__ qft,          // [bh*64+e][1025] fp32
    const unsigned short* __restrict__ Kp,   // [bh][1056][128] bf16
    const unsigned short* __restrict__ Vt,   // [bh][128][1056] bf16
    float* __restrict__ oft)                 // [bh][1025][128] fp32
{
    __shared__ unsigned short Ks[32][136];   // [y][kk], 272B rows (2-way ok)
    __shared__ unsigned short Vs[128][40];   // [ee][y], 80B rows
    __shared__ unsigned short Ps[4][16][40]; // per-wave [m][y]

    int bid  = blockIdx.x;
    int bh   = bid / 17;
    int x0   = (bid % 17) * 64;
    int tid  = threadIdx.x;
    int w    = tid >> 6;
    int lane = tid & 63;
    int qd   = lane >> 4;      // quad
    int col  = lane & 15;

    // ---- Q A-fragments in registers (whole block lifetime) ----
    int xrow = x0 + w * 16 + col;
    int xq   = min(xrow, 1024);
    const float2* qb = qft + (size_t)bh * 64 * NF + xq;
    bhalf8 Are[4], Aim[4];
    #pragma unroll
    for (int ks = 0; ks < 2; ks++)
        #pragma unroll
        for (int j = 0; j < 8; j++) {
            int e = ks * 32 + qd * 8 + j;
            float2 val = qb[(size_t)e * NF];
            unsigned short hr = f2bf(val.x), hi = f2bf(val.y);
            Are[ks][j]     = (short)hr;                 // k<64 : Qr
            Aim[ks][j]     = (short)hi;                 // k<64 : Qi
            Are[ks + 2][j] = (short)hi;                 // k>=64: Qi
            Aim[ks + 2][j] = (short)(hr ^ 0x8000u);     // k>=64: -Qr
        }

    f32x4 O[8];
    #pragma unroll
    for (int n = 0; n < 8; n++) O[n] = (f32x4){0.f, 0.f, 0.f, 0.f};
    float m_i[4], l_i[4];
    #pragma unroll
    for (int r = 0; r < 4; r++) { m_i[r] = -1e30f; l_i[r] = 0.f; }

    const unsigned short* kpb = Kp + (size_t)bh * NYP * 128;
    const unsigned short* vtb = Vt + (size_t)bh * 128 * NYP;

    for (int yt = 0; yt < 33; yt++) {
        int y0 = yt * 32;
        __syncthreads();                       // prev tile reads done
        // ---- stage K tile [32][128] ----
        {
            int yy = tid >> 3, c = tid & 7;
            const uint4* s4 = (const uint4*)(kpb + ((size_t)(y0 + yy)) * 128 + c * 16);
            uint4 a = s4[0], b = s4[1];
            *(uint4*)&Ks[yy][c * 16]     = a;
            *(uint4*)&Ks[yy][c * 16 + 8] = b;
        }
        // ---- stage V tile [128][32] ----
        {
            int ee = tid >> 1, h = tid & 1;
            const uint4* s4 = (const uint4*)(vtb + (size_t)ee * NYP + y0 + h * 16);
            uint4 a = s4[0], b = s4[1];
            *(uint4*)&Vs[ee][h * 16]     = a;
            *(uint4*)&Vs[ee][h * 16 + 8] = b;
        }
        __syncthreads();

        // ---- QK: S_re/S_im [16 x 32] per wave ----
        f32x4 sre[2], sim[2];
        #pragma unroll
        for (int sc = 0; sc < 2; sc++) {
            sre[sc] = (f32x4){0.f, 0.f, 0.f, 0.f};
            sim[sc] = (f32x4){0.f, 0.f, 0.f, 0.f};
        }
        #pragma unroll
        for (int sc = 0; sc < 2; sc++)
            #pragma unroll
            for (int ks = 0; ks < 4; ks++) {
                bhalf8 bfrag = *(const bhalf8*)&Ks[col + 16 * sc][ks * 32 + qd * 8];
                sre[sc] = MFMA16(Are[ks], bfrag, sre[sc]);
                sim[sc] = MFMA16(Aim[ks], bfrag, sim[sc]);
            }

        // ---- online softmax (rows = qd*4+r) ----
        float av[2][4];
        #pragma unroll
        for (int sc = 0; sc < 2; sc++)
            #pragma unroll
            for (int r = 0; r < 4; r++) {
                float re = sre[sc][r], im = sim[sc][r];
                float a = 0.125f * sqrtf(re * re + im * im);
                if (y0 + 16 * sc + col > 1024) a = -1e30f;
                av[sc][r] = a;
            }
        #pragma unroll
        for (int r = 0; r < 4; r++) {
            float mx = fmaxf(av[0][r], av[1][r]);
            mx = fmaxf(mx, __shfl_xor(mx, 1));
            mx = fmaxf(mx, __shfl_xor(mx, 2));
            mx = fmaxf(mx, __shfl_xor(mx, 4));
            mx = fmaxf(mx, __shfl_xor(mx, 8));
            float mn    = fmaxf(m_i[r], mx);
            float alpha = __expf(m_i[r] - mn);
            m_i[r] = mn;
            float p0 = __expf(av[0][r] - mn);
            float p1 = __expf(av[1][r] - mn);
            float ps = p0 + p1;
            ps += __shfl_xor(ps, 1);
            ps += __shfl_xor(ps, 2);
            ps += __shfl_xor(ps, 4);
            ps += __shfl_xor(ps, 8);
            l_i[r] = l_i[r] * alpha + ps;
            #pragma unroll
            for (int n = 0; n < 8; n++) O[n][r] *= alpha;
            Ps[w][qd * 4 + r][col]      = f2bf(p0);
            Ps[w][qd * 4 + r][col + 16] = f2bf(p1);
        }

        // ---- PV: O[16 x 128] += P[16 x 32] . V[32 x 128] ----
        bhalf8 pa = *(const bhalf8*)&Ps[w][col][qd * 8];
        #pragma unroll
        for (int n = 0; n < 8; n++) {
            bhalf8 bv = *(const bhalf8*)&Vs[n * 16 + col][qd * 8];
            O[n] = MFMA16(pa, bv, O[n]);
        }
    }

    // ---- epilogue: normalize, store ----
    #pragma unroll
    for (int r = 0; r < 4; r++) {
        float inv = 1.f / l_i[r];
        int x = x0 + w * 16 + qd * 4 + r;
        if (x <= 1024) {
            float* dst = oft + ((size_t)bh * NF + x) * 128 + col;
            #pragma unroll
            for (int n = 0; n < 8; n++) dst[n * 16] = O[n][r] * inv;
        }
    }
}

// ---------------------------------------------------------------------------
// Inverse rFFT (ortho): Hermitian-extend, iFFT, real part -> [B,T,H,E] fp32.
// ---------------------------------------------------------------------------
__global__ __launch_bounds__(256) void fft_inv(const float* __restrict__ oft,
                                               float* __restrict__ out)
{
    __shared__ float2 buf[NN];
    __shared__ float2 tw[NN / 2];

    int s   = blockIdx.x;
    int tid = threadIdx.x;

    for (int i = tid; i < NN / 2; i += 256) {
        float ang = TWO_PI * (float)i / (float)NN;
        float sv, cv;
        __sincosf(ang, &sv, &cv);
        tw[i] = make_float2(cv, sv);
    }

    int e  = s & 63;
    int bh = s >> 6;
    const float* src = oft + (size_t)bh * NF * 128;
    for (int i = 0; i < 8; i++) {
        int t  = tid + 256 * i;
        int xs = (t <= 1024) ? t : (NN - t);
        float re = src[(size_t)xs * 128 + e];
        float im = src[(size_t)xs * 128 + 64 + e];
        if (t > 1024) im = -im;
        buf[__brev((unsigned)t) >> (32 - LOGN)] = make_float2(re, im);
    }
    __syncthreads();

    fft_stages(buf, tw, tid);

    float* dst =
        out + ((size_t)(s >> 9)) * (2048 * 512) + (((s >> 6) & 7) * 64) + e;
    for (int i = 0; i < 8; i++) {
        int t = tid + 256 * i;
        dst[(size_t)t * 512] = buf[t].x * INV_SQRT_N;
    }
}

// ---------------------------------------------------------------------------
extern "C" void kernel_launch(void* const* d_in, const int* in_sizes, int n_in,
                              void* d_out, int out_size, void* d_ws, size_t ws_size,
                              hipStream_t stream)
{
    const float* q = (const float*)d_in[0];
    const float* k = (const float*)d_in[1];
    const float* v = (const float*)d_in[2];
    float* out = (float*)d_out;

    char* ws = (char*)d_ws;
    const size_t ftsz = (size_t)32 * 64 * NF * sizeof(float2);          // 16.79 MB
    const size_t kpsz = (size_t)32 * NYP * 128 * sizeof(unsigned short); // 8.65 MB
    float2* qft = (float2*)ws;
    float2* kft = (float2*)(ws + ftsz);
    float*  oft = (float*)(ws + ftsz);   // aliases kft: kft dead after kpack
    unsigned short* Kp = (unsigned short*)(ws + 2 * ftsz);
    unsigned short* Vt = (unsigned short*)(ws + 2 * ftsz + kpsz);

    hipLaunchKernelGGL(fft_fwd, dim3(3 * 2048), dim3(256), 0, stream,
                       q, k, v, qft, kft, Vt);
    hipLaunchKernelGGL(kpack, dim3(33, 32), dim3(256), 0, stream, kft, Kp);
    hipLaunchKernelGGL(flash_mfma, dim3(17 * 32), dim3(256), 0, stream,
                       qft, Kp, Vt, oft);
    hipLaunchKernelGGL(fft_inv, dim3(2048), dim3(256), 0, stream, oft, out);
}